// Round 1
// baseline (995.273 us; speedup 1.0000x reference)
//
#include <hip/hip_runtime.h>
#include <math.h>

#define Bdim 256
#define Sdim 512
#define Hdim 1024
#define Wdim 64
#define BK 32
#define JTILE 256   // j's per scores block
#define NJT 4
#define MTILE 128   // 2 b x 64 w rows per scores block
#define KC 4        // K-split for hcw kernel

// ws layout (floats): scores [NJT][B][W] = 65536 ; hcw partials [KC][B][H]
#define WS_SCORES_F (NJT * Bdim * Wdim)
#define WS_NEED_BYTES ((size_t)(WS_SCORES_F + KC * Bdim * Hdim) * 4)

// LDS geometry for k_scores
#define ASTRIDE 140                    // 128 rows + 4*(row>>5) pad -> all reads/stores <=2-way
#define AS_F (BK * ASTRIDE)            // 4480 floats
#define SMEM_F (AS_F + BK * JTILE)     // 4480 + 8192 = 12672 floats = 50.7 KB
#define HC0_OFF 0
#define HCW_OFF 2048
#define VS_OFF  2560

// ---------------------------------------------------------------------------
// Kernel 0: hcw[b][j] partials = sum over 256 k of hc[b,k]*Wa[j,k]
// grid (4 jt, 16 bt, KC), block 256. Tile: 16 b x 256 j, per-thread 4x4.
// ---------------------------------------------------------------------------
__global__ __launch_bounds__(256) void k_hcw(
    const float* __restrict__ hc, const float* __restrict__ Wa,
    float* __restrict__ part)
{
  const int jt = blockIdx.x, bt = blockIdx.y, kc = blockIdx.z;
  const int t = threadIdx.x;
  const int b0 = bt * 16;
  const int kb = kc * 256;
  __shared__ float As[BK][20];     // stride 20 -> store banks r+{0,16}: 2-way
  __shared__ float Bs[BK][256];
  const int tb = t & 3, tj = t >> 2;
  float acc[4][4] = {{0.f}};
  const float* brow = Wa + (size_t)(jt * 256 + t) * (2 * Hdim) + kb;  // W1 half
  const int r = t & 15, kq = t >> 4;
  for (int k0 = 0; k0 < 256; k0 += BK) {
    float4 bld[8];
    #pragma unroll
    for (int q = 0; q < 8; ++q) bld[q] = *(const float4*)(brow + k0 + q * 4);
    float4 ald = make_float4(0.f, 0.f, 0.f, 0.f);
    if (t < 128) ald = *(const float4*)(hc + (size_t)(b0 + r) * Hdim + kb + k0 + kq * 4);
    __syncthreads();
    #pragma unroll
    for (int q = 0; q < 8; ++q)
      #pragma unroll
      for (int e = 0; e < 4; ++e)
        Bs[q * 4 + e][t] = ((const float*)&bld[q])[e];
    if (t < 128) {
      #pragma unroll
      for (int e = 0; e < 4; ++e) As[kq * 4 + e][r] = ((const float*)&ald)[e];
    }
    __syncthreads();
    #pragma unroll 8
    for (int k = 0; k < BK; ++k) {
      const float4 av = *(const float4*)&As[k][tb * 4];
      const float4 bv = *(const float4*)&Bs[k][tj * 4];
      const float A4[4] = {av.x, av.y, av.z, av.w};
      const float B4[4] = {bv.x, bv.y, bv.z, bv.w};
      #pragma unroll
      for (int i = 0; i < 4; ++i)
        #pragma unroll
        for (int jj = 0; jj < 4; ++jj)
          acc[i][jj] = fmaf(A4[i], B4[jj], acc[i][jj]);
    }
  }
  float* outp = part + (size_t)kc * (Bdim * Hdim);
  #pragma unroll
  for (int i = 0; i < 4; ++i)
    #pragma unroll
    for (int jj = 0; jj < 4; ++jj)
      outp[(size_t)(b0 + tb * 4 + i) * Hdim + jt * 256 + tj * 4 + jj] = acc[i][jj];
}

// ---------------------------------------------------------------------------
// Kernel 1: scores GEMM. grid (4 jt, 128 b-pairs), block 256.
// Tile: M=128 rows (2 b x 64 w), N=256 j, K=1024. Per-thread 8w x 16j.
// W2 traffic: 512 blocks x 1 MB (vs 1024 x 2 MB before).
// ---------------------------------------------------------------------------
template<int USE_PART>
__global__ __launch_bounds__(256, 2) void k_scores(
    const float* __restrict__ inputs, const float* __restrict__ hc,
    const float* __restrict__ Wa, const float* __restrict__ ba,
    const float* __restrict__ v, const int* __restrict__ slen,
    float* __restrict__ ws_scores, const float* __restrict__ part)
{
  const int jt = blockIdx.x;
  const int b0 = blockIdx.y * 2;
  const int t = threadIdx.x;
  __shared__ float smem[SMEM_F];
  float* Bsb = smem + AS_F;

  const int tw = t & 15, tj = t >> 4;
  const int w0 = tw * 8, j0 = tj * 16;
  const int awp = w0 + 4 * (tw >> 2);      // padded A read base (contiguous 8)

  // A staging: 2 lanes per row, 128B contiguous global segments
  const int ar = t >> 1, ah = t & 1;
  const int absub = ar >> 6;
  const int slA = slen[b0 + absub];
  const float* arow = inputs +
      ((size_t)(b0 + absub) * Sdim + slA - Wdim + (ar & 63)) * Hdim + ah * 16;
  const int aphys = ar + 4 * (ar >> 5);    // padded store column
  // B staging: thread t <-> W2 row jt*256+t (full line per lane, store col=t: 2-way)
  const float* brow = Wa + (size_t)(jt * JTILE + t) * (2 * Hdim) + Hdim;

  float acc[8][16];
  #pragma unroll
  for (int i = 0; i < 8; ++i)
    #pragma unroll
    for (int jj = 0; jj < 16; ++jj) acc[i][jj] = 0.f;

  for (int k0 = 0; k0 < Hdim; k0 += BK) {
    float4 a_ld[4];
    #pragma unroll
    for (int c = 0; c < 4; ++c) a_ld[c] = *(const float4*)(arow + k0 + c * 4);
    float4 b_ld[8];
    #pragma unroll
    for (int q = 0; q < 8; ++q) b_ld[q] = *(const float4*)(brow + k0 + q * 4);
    __syncthreads();
    #pragma unroll
    for (int c = 0; c < 4; ++c)
      #pragma unroll
      for (int e = 0; e < 4; ++e)
        smem[(ah * 16 + c * 4 + e) * ASTRIDE + aphys] = ((const float*)&a_ld[c])[e];
    #pragma unroll
    for (int q = 0; q < 8; ++q)
      #pragma unroll
      for (int e = 0; e < 4; ++e)
        Bsb[(q * 4 + e) * JTILE + t] = ((const float*)&b_ld[q])[e];
    __syncthreads();
    #pragma unroll 8
    for (int k = 0; k < BK; ++k) {
      const float* Ak = smem + k * ASTRIDE;
      const float* Bk = Bsb + k * JTILE;
      const float4 av0 = *(const float4*)(Ak + awp);
      const float4 av1 = *(const float4*)(Ak + awp + 4);
      const float4 bv0 = *(const float4*)(Bk + j0);
      const float4 bv1 = *(const float4*)(Bk + j0 + 4);
      const float4 bv2 = *(const float4*)(Bk + j0 + 8);
      const float4 bv3 = *(const float4*)(Bk + j0 + 12);
      const float A8[8]  = {av0.x, av0.y, av0.z, av0.w, av1.x, av1.y, av1.z, av1.w};
      const float B16[16] = {bv0.x, bv0.y, bv0.z, bv0.w, bv1.x, bv1.y, bv1.z, bv1.w,
                             bv2.x, bv2.y, bv2.z, bv2.w, bv3.x, bv3.y, bv3.z, bv3.w};
      #pragma unroll
      for (int wi = 0; wi < 8; ++wi)
        #pragma unroll
        for (int ji = 0; ji < 16; ++ji)
          acc[wi][ji] = fmaf(A8[wi], B16[ji], acc[wi][ji]);
    }
  }

  __syncthreads();   // smem reuse below

  const int j = jt * JTILE + t;
  if (USE_PART) {
    float h0 = ba[j], h1 = ba[j];
    #pragma unroll
    for (int kc = 0; kc < KC; ++kc) {
      h0 += part[(size_t)kc * (Bdim * Hdim) + (size_t)b0 * Hdim + j];
      h1 += part[(size_t)kc * (Bdim * Hdim) + (size_t)(b0 + 1) * Hdim + j];
    }
    smem[HCW_OFF + t] = h0;
    smem[HCW_OFF + 256 + t] = h1;
    smem[VS_OFF + t] = v[j];
  } else {
    // fallback: in-block hc @ W1^T (2 b's share each W1 row read)
    for (int i = t; i < 2 * Hdim; i += 256) smem[HC0_OFF + i] = hc[(size_t)b0 * Hdim + i];
    __syncthreads();
    const float* w1row = Wa + (size_t)j * (2 * Hdim);
    float s0 = 0.f, s1 = 0.f;
    #pragma unroll 4
    for (int k = 0; k < Hdim; k += 4) {
      const float4 wv  = *(const float4*)(w1row + k);
      const float4 h0v = *(const float4*)(smem + HC0_OFF + k);
      const float4 h1v = *(const float4*)(smem + HC0_OFF + Hdim + k);
      s0 = fmaf(wv.x, h0v.x, s0); s0 = fmaf(wv.y, h0v.y, s0);
      s0 = fmaf(wv.z, h0v.z, s0); s0 = fmaf(wv.w, h0v.w, s0);
      s1 = fmaf(wv.x, h1v.x, s1); s1 = fmaf(wv.y, h1v.y, s1);
      s1 = fmaf(wv.z, h1v.z, s1); s1 = fmaf(wv.w, h1v.w, s1);
    }
    __syncthreads();
    smem[HCW_OFF + t] = s0 + ba[j];
    smem[HCW_OFF + 256 + t] = s1 + ba[j];
    smem[VS_OFF + t] = v[j];
  }
  __syncthreads();

  // epilogue: tanh + v-dot; each thread's 8 w-rows are all in one b-sub
  const int bsub = tw >> 3;
  float sloc[8] = {0.f, 0.f, 0.f, 0.f, 0.f, 0.f, 0.f, 0.f};
  #pragma unroll
  for (int ji = 0; ji < 16; ++ji) {
    const float hw = smem[HCW_OFF + bsub * 256 + j0 + ji];
    const float vj = smem[VS_OFF + j0 + ji];
    #pragma unroll
    for (int wi = 0; wi < 8; ++wi)
      sloc[wi] = fmaf(vj, tanhf(acc[wi][ji] + hw), sloc[wi]);
  }
  float* red = smem + AS_F;          // 16 x 128, Bs region (disjoint from hcw/v)
  #pragma unroll
  for (int wi = 0; wi < 8; ++wi) red[tj * MTILE + w0 + wi] = sloc[wi];
  __syncthreads();
  if (t < MTILE) {
    float s = 0.f;
    #pragma unroll
    for (int p = 0; p < 16; ++p) s += red[p * MTILE + t];
    ws_scores[(size_t)jt * (Bdim * Wdim) + (size_t)(b0 + (t >> 6)) * Wdim + (t & 63)] = s;
  }
}

// ---------------------------------------------------------------------------
// Kernel 2: softmax (W=64, one wave) + context + par.  (unchanged)
// ---------------------------------------------------------------------------
__global__ __launch_bounds__(256) void k_finish(
    const float* __restrict__ inputs, const int* __restrict__ slen,
    const int* __restrict__ parent, const float* __restrict__ ws_scores,
    float* __restrict__ out)
{
  const int b = blockIdx.x;
  const int c = blockIdx.y;
  const int t = threadIdx.x;
  const int sl = slen[b];
  __shared__ float attn[64];

  if (t < 64) {
    float s = ws_scores[b * Wdim + t]
            + ws_scores[1 * (Bdim * Wdim) + b * Wdim + t]
            + ws_scores[2 * (Bdim * Wdim) + b * Wdim + t]
            + ws_scores[3 * (Bdim * Wdim) + b * Wdim + t];
    float mx = s;
    #pragma unroll
    for (int off = 32; off > 0; off >>= 1) mx = fmaxf(mx, __shfl_xor(mx, off));
    const float e = __expf(s - mx);
    float sm = e;
    #pragma unroll
    for (int off = 32; off > 0; off >>= 1) sm += __shfl_xor(sm, off);
    const float a = e / sm;
    if (c == 0) out[b * Wdim + t] = a;
    attn[t] = a;
  }
  __syncthreads();

  const float* base = inputs + ((size_t)b * Sdim + sl - Wdim) * Hdim + c * 256;
  float a0 = 0.f;
  #pragma unroll 8
  for (int w = 0; w < Wdim; ++w)
    a0 = fmaf(attn[w], base[(size_t)w * Hdim + t], a0);
  out[Bdim * Wdim + (size_t)b * Hdim + c * 256 + t] = a0;

  const float* pr = inputs + ((size_t)b * Sdim + sl - parent[b] - 1) * Hdim + c * 256;
  out[Bdim * Wdim + Bdim * Hdim + (size_t)b * Hdim + c * 256 + t] = pr[t];
}

extern "C" void kernel_launch(void* const* d_in, const int* in_sizes, int n_in,
                              void* d_out, int out_size, void* d_ws, size_t ws_size,
                              hipStream_t stream) {
  const float* inputs = (const float*)d_in[0];
  const float* hc     = (const float*)d_in[1];
  const float* Wa     = (const float*)d_in[2];
  const float* ba     = (const float*)d_in[3];
  const float* v      = (const float*)d_in[4];
  const int*   slen   = (const int*)d_in[5];
  const int*   parent = (const int*)d_in[6];
  float* out = (float*)d_out;
  float* ws  = (float*)d_ws;

  const bool use_part = (ws_size >= WS_NEED_BYTES);
  if (use_part) {
    k_hcw<<<dim3(NJT, 16, KC), 256, 0, stream>>>(hc, Wa, ws + WS_SCORES_F);
    k_scores<1><<<dim3(NJT, Bdim / 2), 256, 0, stream>>>(
        inputs, hc, Wa, ba, v, slen, ws, ws + WS_SCORES_F);
  } else {
    k_scores<0><<<dim3(NJT, Bdim / 2), 256, 0, stream>>>(
        inputs, hc, Wa, ba, v, slen, ws, nullptr);
  }
  k_finish<<<dim3(Bdim, 4), 256, 0, stream>>>(inputs, slen, parent, ws, out);
}

// Round 2
// 818.165 us; speedup vs baseline: 1.2165x; 1.2165x over previous
//
#include <hip/hip_runtime.h>
#include <math.h>

#define Bdim 256
#define Sdim 512
#define Hdim 1024
#define Wdim 64
#define BK 32
#define JTILE 256
#define NJT 4
#define MTILE 128
#define KC 4

typedef __attribute__((ext_vector_type(8))) short bf16x8;
typedef __attribute__((ext_vector_type(4))) float f32x4;

// ws layout (floats):
//   [0, 65536)                      scores [NJT][B][W]
//   [65536, 65536+1048576)          hcw partials [KC][B][H]
//   [1114112, 1114112+1048576)      W2 split bf16 (hi/lo interleaved per 32-k chunk)
#define WS_SCORES_F (NJT * Bdim * Wdim)
#define WS_PART_F   (KC * Bdim * Hdim)
#define WS_WSP_F    (Hdim * Hdim / 2)            // 2M bf16 = 1M floats
#define WS_NEED_BYTES  ((size_t)(WS_SCORES_F + WS_PART_F) * 4)
#define WS_MFMA_BYTES  ((size_t)(WS_SCORES_F + WS_PART_F + WS_WSP_F) * 4)

// old fp32 path LDS geometry
#define ASTRIDE 140
#define AS_F (BK * ASTRIDE)
#define SMEM_F (AS_F + BK * JTILE)
#define HC0_OFF 0
#define HCW_OFF 2048
#define VS_OFF  2560

__device__ __forceinline__ unsigned pk2(unsigned short a, unsigned short b) {
  return (unsigned)a | ((unsigned)b << 16);
}

// ---------------------------------------------------------------------------
// Kernel P: split W2 (= Wa[:, H:2H]) into bf16 hi/lo, layout per (j, kc32):
// [32 hi bf16 (64B)][32 lo bf16 (64B)]  -> row stride 2048 ushorts per j.
// ---------------------------------------------------------------------------
__global__ __launch_bounds__(256) void k_wsplit(
    const float* __restrict__ Wa, unsigned short* __restrict__ wsp)
{
  const int j = blockIdx.x;
  const int t = threadIdx.x;          // handles k = 4t..4t+3
  const float4 xv = *(const float4*)(Wa + (size_t)j * (2 * Hdim) + Hdim + 4 * t);
  unsigned short h[4], l[4];
  #pragma unroll
  for (int e = 0; e < 4; ++e) {
    const float x = ((const float*)&xv)[e];
    const unsigned u = __float_as_uint(x);
    const float hif = __uint_as_float(u & 0xFFFF0000u);
    const float lof = x - hif;
    h[e] = (unsigned short)(u >> 16);
    l[e] = (unsigned short)(__float_as_uint(lof) >> 16);
  }
  const int kc = (4 * t) >> 5, ki = (4 * t) & 31;
  unsigned short* base = wsp + (size_t)j * 2048 + kc * 64 + ki;
  *(ushort4*)(base)      = make_ushort4(h[0], h[1], h[2], h[3]);
  *(ushort4*)(base + 32) = make_ushort4(l[0], l[1], l[2], l[3]);
}

// ---------------------------------------------------------------------------
// Kernel 0: hcw partials (unchanged, verified)
// ---------------------------------------------------------------------------
__global__ __launch_bounds__(256) void k_hcw(
    const float* __restrict__ hc, const float* __restrict__ Wa,
    float* __restrict__ part)
{
  const int jt = blockIdx.x, bt = blockIdx.y, kc = blockIdx.z;
  const int t = threadIdx.x;
  const int b0 = bt * 16;
  const int kb = kc * 256;
  __shared__ float As[BK][20];
  __shared__ float Bs[BK][256];
  const int tb = t & 3, tj = t >> 2;
  float acc[4][4] = {{0.f}};
  const float* brow = Wa + (size_t)(jt * 256 + t) * (2 * Hdim) + kb;
  const int r = t & 15, kq = t >> 4;
  for (int k0 = 0; k0 < 256; k0 += BK) {
    float4 bld[8];
    #pragma unroll
    for (int q = 0; q < 8; ++q) bld[q] = *(const float4*)(brow + k0 + q * 4);
    float4 ald = make_float4(0.f, 0.f, 0.f, 0.f);
    if (t < 128) ald = *(const float4*)(hc + (size_t)(b0 + r) * Hdim + kb + k0 + kq * 4);
    __syncthreads();
    #pragma unroll
    for (int q = 0; q < 8; ++q)
      #pragma unroll
      for (int e = 0; e < 4; ++e)
        Bs[q * 4 + e][t] = ((const float*)&bld[q])[e];
    if (t < 128) {
      #pragma unroll
      for (int e = 0; e < 4; ++e) As[kq * 4 + e][r] = ((const float*)&ald)[e];
    }
    __syncthreads();
    #pragma unroll 8
    for (int k = 0; k < BK; ++k) {
      const float4 av = *(const float4*)&As[k][tb * 4];
      const float4 bv = *(const float4*)&Bs[k][tj * 4];
      const float A4[4] = {av.x, av.y, av.z, av.w};
      const float B4[4] = {bv.x, bv.y, bv.z, bv.w};
      #pragma unroll
      for (int i = 0; i < 4; ++i)
        #pragma unroll
        for (int jj = 0; jj < 4; ++jj)
          acc[i][jj] = fmaf(A4[i], B4[jj], acc[i][jj]);
    }
  }
  float* outp = part + (size_t)kc * (Bdim * Hdim);
  #pragma unroll
  for (int i = 0; i < 4; ++i)
    #pragma unroll
    for (int jj = 0; jj < 4; ++jj)
      outp[(size_t)(b0 + tb * 4 + i) * Hdim + jt * 256 + tj * 4 + jj] = acc[i][jj];
}

// ---------------------------------------------------------------------------
// Kernel 1 (MFMA): scores via bf16x3 split GEMM.
// grid (4 jt, 64), block 512 (8 waves, 4M x 2N). Tile M=256 (4 b x 64 w),
// N=256 j, K-step 32. A split in-kernel; B pre-split (wsp).
// LDS: A 256x128B + B 256x128B, XOR slot-swizzle (slot ^ (row&7)) -> 2-way.
// ---------------------------------------------------------------------------
__global__ __launch_bounds__(512) void k_scores_mfma(
    const float* __restrict__ inputs, const float* __restrict__ ba,
    const float* __restrict__ v, const int* __restrict__ slen,
    float* __restrict__ ws_scores, const float* __restrict__ part,
    const unsigned short* __restrict__ wsp)
{
  const int jt = blockIdx.x;
  const int b0 = blockIdx.y * 4;
  const int t = threadIdx.x;
  const int lane = t & 63, wv = t >> 6, wm = wv >> 1, wn = wv & 1;

  __shared__ uint4 lds4[65536 / 16];
  char* As = (char*)lds4;
  char* Bs = (char*)lds4 + 32768;

  // ---- staging addresses ----
  const int ar = t >> 1, ah = t & 1;          // A: 2 threads/row, 16 floats each
  const int ab = ar >> 6;                      // b_local
  const int slA = slen[b0 + ab];
  const float* aptr = inputs +
      ((size_t)(b0 + ab) * Sdim + slA - Wdim + (ar & 63)) * Hdim + ah * 16;
  const int arw = ar & 7;
  char* aw0 = As + ar * 128;
  const int bj = t >> 1, bc = t & 1;           // B: 2 threads/row (hi/lo comp)
  const unsigned short* bptr = wsp + (size_t)(jt * 256 + bj) * 2048 + bc * 32;
  const int bjw = bj & 7;
  char* bw0 = Bs + bj * 128;

  // ---- fragment read offsets (static-indexed) ----
  int aoff[4][2], boff[8][2];
  #pragma unroll
  for (int mt = 0; mt < 4; ++mt) {
    const int row = wm * 64 + mt * 16 + (lane & 15);
    const int s0 = lane >> 4;
    aoff[mt][0] = row * 128 + ((s0 ^ (row & 7)) << 4);
    aoff[mt][1] = row * 128 + (((s0 + 4) ^ (row & 7)) << 4);
  }
  #pragma unroll
  for (int nt = 0; nt < 8; ++nt) {
    const int row = wn * 128 + nt * 16 + (lane & 15);
    const int s0 = lane >> 4;
    boff[nt][0] = row * 128 + ((s0 ^ (row & 7)) << 4);
    boff[nt][1] = row * 128 + (((s0 + 4) ^ (row & 7)) << 4);
  }

  f32x4 acc[4][8];
  #pragma unroll
  for (int mt = 0; mt < 4; ++mt)
    #pragma unroll
    for (int nt = 0; nt < 8; ++nt) {
      f32x4 z = {0.f, 0.f, 0.f, 0.f};
      acc[mt][nt] = z;
    }

  float4 a_ld[4];
  uint4  b_ld[4];
  #pragma unroll
  for (int c = 0; c < 4; ++c) a_ld[c] = *(const float4*)(aptr + c * 4);
  #pragma unroll
  for (int q = 0; q < 4; ++q) b_ld[q] = *(const uint4*)(bptr + q * 8);

  for (int k0 = 0; k0 < Hdim; k0 += 32) {
    __syncthreads();                 // previous compute done; LDS writable
    // convert A fp32 -> bf16 hi/lo (truncation split)
    unsigned short h[16], l[16];
    #pragma unroll
    for (int c = 0; c < 4; ++c)
      #pragma unroll
      for (int e = 0; e < 4; ++e) {
        const float x = ((const float*)&a_ld[c])[e];
        const unsigned u = __float_as_uint(x);
        const float hif = __uint_as_float(u & 0xFFFF0000u);
        const float lof = x - hif;
        h[c * 4 + e] = (unsigned short)(u >> 16);
        l[c * 4 + e] = (unsigned short)(__float_as_uint(lof) >> 16);
      }
    uint4 H0 = make_uint4(pk2(h[0], h[1]), pk2(h[2], h[3]), pk2(h[4], h[5]), pk2(h[6], h[7]));
    uint4 H1 = make_uint4(pk2(h[8], h[9]), pk2(h[10], h[11]), pk2(h[12], h[13]), pk2(h[14], h[15]));
    uint4 L0 = make_uint4(pk2(l[0], l[1]), pk2(l[2], l[3]), pk2(l[4], l[5]), pk2(l[6], l[7]));
    uint4 L1 = make_uint4(pk2(l[8], l[9]), pk2(l[10], l[11]), pk2(l[12], l[13]), pk2(l[14], l[15]));
    *(uint4*)(aw0 + (((2 * ah + 0) ^ arw) << 4)) = H0;
    *(uint4*)(aw0 + (((2 * ah + 1) ^ arw) << 4)) = H1;
    *(uint4*)(aw0 + (((4 + 2 * ah + 0) ^ arw) << 4)) = L0;
    *(uint4*)(aw0 + (((4 + 2 * ah + 1) ^ arw) << 4)) = L1;
    #pragma unroll
    for (int q = 0; q < 4; ++q)
      *(uint4*)(bw0 + (((bc * 4 + q) ^ bjw) << 4)) = b_ld[q];
    // prefetch next tile (latency hides under this step's MFMA)
    if (k0 + 32 < Hdim) {
      #pragma unroll
      for (int c = 0; c < 4; ++c) a_ld[c] = *(const float4*)(aptr + k0 + 32 + c * 4);
      const int kc = (k0 + 32) >> 5;
      #pragma unroll
      for (int q = 0; q < 4; ++q) b_ld[q] = *(const uint4*)(bptr + kc * 64 + q * 8);
    }
    __syncthreads();                 // LDS tile ready
    // compute: 8 A-reads + 16 B-reads feed 96 MFMA
    bf16x8 ahf[4], alf[4];
    #pragma unroll
    for (int mt = 0; mt < 4; ++mt) {
      ahf[mt] = *(const bf16x8*)(As + aoff[mt][0]);
      alf[mt] = *(const bf16x8*)(As + aoff[mt][1]);
    }
    #pragma unroll
    for (int nt = 0; nt < 8; ++nt) {
      const bf16x8 bh = *(const bf16x8*)(Bs + boff[nt][0]);
      const bf16x8 bl = *(const bf16x8*)(Bs + boff[nt][1]);
      #pragma unroll
      for (int mt = 0; mt < 4; ++mt) {
        acc[mt][nt] = __builtin_amdgcn_mfma_f32_16x16x32_bf16(ahf[mt], bh, acc[mt][nt], 0, 0, 0);
        acc[mt][nt] = __builtin_amdgcn_mfma_f32_16x16x32_bf16(alf[mt], bh, acc[mt][nt], 0, 0, 0);
        acc[mt][nt] = __builtin_amdgcn_mfma_f32_16x16x32_bf16(ahf[mt], bl, acc[mt][nt], 0, 0, 0);
      }
    }
  }

  // ---- epilogue ----
  __syncthreads();
  float* scr   = (float*)lds4;        // reuse A region
  float* hcw_s = scr;                  // [4][256]
  float* v_s   = scr + 1024;           // [256]
  float* red   = scr + 1280;           // [2][256]
  for (int idx = t; idx < 1024; idx += 512) {
    const int bb = idx >> 8, jj = idx & 255;
    const int jg = jt * 256 + jj;
    float s = ba[jg];
    #pragma unroll
    for (int kc = 0; kc < KC; ++kc)
      s += part[(size_t)kc * (Bdim * Hdim) + (size_t)(b0 + bb) * Hdim + jg];
    hcw_s[idx] = s;
  }
  if (t < 256) v_s[t] = v[jt * 256 + t];
  __syncthreads();

  float sred[4][4];
  #pragma unroll
  for (int mt = 0; mt < 4; ++mt)
    #pragma unroll
    for (int r = 0; r < 4; ++r) sred[mt][r] = 0.f;
  #pragma unroll
  for (int nt = 0; nt < 8; ++nt) {
    const int col = wn * 128 + nt * 16 + (lane & 15);
    const float hw0 = hcw_s[wm * 256 + col];
    const float vj = v_s[col];
    #pragma unroll
    for (int mt = 0; mt < 4; ++mt)
      #pragma unroll
      for (int r = 0; r < 4; ++r) {
        const float s = ((const float*)&acc[mt][nt])[r] + hw0;
        sred[mt][r] = fmaf(vj, tanhf(s), sred[mt][r]);
      }
  }
  #pragma unroll
  for (int mt = 0; mt < 4; ++mt)
    #pragma unroll
    for (int r = 0; r < 4; ++r) {
      float x = sred[mt][r];
      x += __shfl_xor(x, 1); x += __shfl_xor(x, 2);
      x += __shfl_xor(x, 4); x += __shfl_xor(x, 8);
      sred[mt][r] = x;
    }
  if ((lane & 15) == 0) {
    #pragma unroll
    for (int mt = 0; mt < 4; ++mt)
      #pragma unroll
      for (int r = 0; r < 4; ++r)
        red[wn * 256 + wm * 64 + mt * 16 + (lane >> 4) * 4 + r] = sred[mt][r];
  }
  __syncthreads();
  if (t < 256) {
    const float s = red[t] + red[256 + t];
    ws_scores[(size_t)jt * (Bdim * Wdim) + (size_t)(b0 + (t >> 6)) * Wdim + (t & 63)] = s;
  }
}

// ---------------------------------------------------------------------------
// Old fp32 scores kernel (fallback if workspace too small) — verified path.
// ---------------------------------------------------------------------------
template<int USE_PART>
__global__ __launch_bounds__(256, 2) void k_scores(
    const float* __restrict__ inputs, const float* __restrict__ hc,
    const float* __restrict__ Wa, const float* __restrict__ ba,
    const float* __restrict__ v, const int* __restrict__ slen,
    float* __restrict__ ws_scores, const float* __restrict__ part)
{
  const int jt = blockIdx.x;
  const int b0 = blockIdx.y * 2;
  const int t = threadIdx.x;
  __shared__ float smem[SMEM_F];
  float* Bsb = smem + AS_F;

  const int tw = t & 15, tj = t >> 4;
  const int w0 = tw * 8, j0 = tj * 16;
  const int awp = w0 + 4 * (tw >> 2);

  const int ar = t >> 1, ah = t & 1;
  const int absub = ar >> 6;
  const int slA = slen[b0 + absub];
  const float* arow = inputs +
      ((size_t)(b0 + absub) * Sdim + slA - Wdim + (ar & 63)) * Hdim + ah * 16;
  const int aphys = ar + 4 * (ar >> 5);
  const float* brow = Wa + (size_t)(jt * JTILE + t) * (2 * Hdim) + Hdim;

  float acc[8][16];
  #pragma unroll
  for (int i = 0; i < 8; ++i)
    #pragma unroll
    for (int jj = 0; jj < 16; ++jj) acc[i][jj] = 0.f;

  for (int k0 = 0; k0 < Hdim; k0 += BK) {
    float4 a_ld[4];
    #pragma unroll
    for (int c = 0; c < 4; ++c) a_ld[c] = *(const float4*)(arow + k0 + c * 4);
    float4 b_ld[8];
    #pragma unroll
    for (int q = 0; q < 8; ++q) b_ld[q] = *(const float4*)(brow + k0 + q * 4);
    __syncthreads();
    #pragma unroll
    for (int c = 0; c < 4; ++c)
      #pragma unroll
      for (int e = 0; e < 4; ++e)
        smem[(ah * 16 + c * 4 + e) * ASTRIDE + aphys] = ((const float*)&a_ld[c])[e];
    #pragma unroll
    for (int q = 0; q < 8; ++q)
      #pragma unroll
      for (int e = 0; e < 4; ++e)
        Bsb[(q * 4 + e) * JTILE + t] = ((const float*)&b_ld[q])[e];
    __syncthreads();
    #pragma unroll 8
    for (int k = 0; k < BK; ++k) {
      const float* Ak = smem + k * ASTRIDE;
      const float* Bk = Bsb + k * JTILE;
      const float4 av0 = *(const float4*)(Ak + awp);
      const float4 av1 = *(const float4*)(Ak + awp + 4);
      const float4 bv0 = *(const float4*)(Bk + j0);
      const float4 bv1 = *(const float4*)(Bk + j0 + 4);
      const float4 bv2 = *(const float4*)(Bk + j0 + 8);
      const float4 bv3 = *(const float4*)(Bk + j0 + 12);
      const float A8[8]  = {av0.x, av0.y, av0.z, av0.w, av1.x, av1.y, av1.z, av1.w};
      const float B16[16] = {bv0.x, bv0.y, bv0.z, bv0.w, bv1.x, bv1.y, bv1.z, bv1.w,
                             bv2.x, bv2.y, bv2.z, bv2.w, bv3.x, bv3.y, bv3.z, bv3.w};
      #pragma unroll
      for (int wi = 0; wi < 8; ++wi)
        #pragma unroll
        for (int ji = 0; ji < 16; ++ji)
          acc[wi][ji] = fmaf(A8[wi], B16[ji], acc[wi][ji]);
    }
  }

  __syncthreads();
  const int j = jt * JTILE + t;
  if (USE_PART) {
    float h0 = ba[j], h1 = ba[j];
    #pragma unroll
    for (int kc = 0; kc < KC; ++kc) {
      h0 += part[(size_t)kc * (Bdim * Hdim) + (size_t)b0 * Hdim + j];
      h1 += part[(size_t)kc * (Bdim * Hdim) + (size_t)(b0 + 1) * Hdim + j];
    }
    smem[HCW_OFF + t] = h0;
    smem[HCW_OFF + 256 + t] = h1;
    smem[VS_OFF + t] = v[j];
  } else {
    for (int i = t; i < 2 * Hdim; i += 256) smem[HC0_OFF + i] = hc[(size_t)b0 * Hdim + i];
    __syncthreads();
    const float* w1row = Wa + (size_t)j * (2 * Hdim);
    float s0 = 0.f, s1 = 0.f;
    #pragma unroll 4
    for (int k = 0; k < Hdim; k += 4) {
      const float4 wv  = *(const float4*)(w1row + k);
      const float4 h0v = *(const float4*)(smem + HC0_OFF + k);
      const float4 h1v = *(const float4*)(smem + HC0_OFF + Hdim + k);
      s0 = fmaf(wv.x, h0v.x, s0); s0 = fmaf(wv.y, h0v.y, s0);
      s0 = fmaf(wv.z, h0v.z, s0); s0 = fmaf(wv.w, h0v.w, s0);
      s1 = fmaf(wv.x, h1v.x, s1); s1 = fmaf(wv.y, h1v.y, s1);
      s1 = fmaf(wv.z, h1v.z, s1); s1 = fmaf(wv.w, h1v.w, s1);
    }
    __syncthreads();
    smem[HCW_OFF + t] = s0 + ba[j];
    smem[HCW_OFF + 256 + t] = s1 + ba[j];
    smem[VS_OFF + t] = v[j];
  }
  __syncthreads();

  const int bsub = tw >> 3;
  float sloc[8] = {0.f, 0.f, 0.f, 0.f, 0.f, 0.f, 0.f, 0.f};
  #pragma unroll
  for (int ji = 0; ji < 16; ++ji) {
    const float hw = smem[HCW_OFF + bsub * 256 + j0 + ji];
    const float vj = smem[VS_OFF + j0 + ji];
    #pragma unroll
    for (int wi = 0; wi < 8; ++wi)
      sloc[wi] = fmaf(vj, tanhf(acc[wi][ji] + hw), sloc[wi]);
  }
  float* red = smem + AS_F;
  #pragma unroll
  for (int wi = 0; wi < 8; ++wi) red[tj * MTILE + w0 + wi] = sloc[wi];
  __syncthreads();
  if (t < MTILE) {
    float s = 0.f;
    #pragma unroll
    for (int p = 0; p < 16; ++p) s += red[p * MTILE + t];
    ws_scores[(size_t)jt * (Bdim * Wdim) + (size_t)(b0 + (t >> 6)) * Wdim + (t & 63)] = s;
  }
}

// ---------------------------------------------------------------------------
// Kernel 2: softmax + context + par (unchanged, verified)
// ---------------------------------------------------------------------------
__global__ __launch_bounds__(256) void k_finish(
    const float* __restrict__ inputs, const int* __restrict__ slen,
    const int* __restrict__ parent, const float* __restrict__ ws_scores,
    float* __restrict__ out)
{
  const int b = blockIdx.x;
  const int c = blockIdx.y;
  const int t = threadIdx.x;
  const int sl = slen[b];
  __shared__ float attn[64];

  if (t < 64) {
    float s = ws_scores[b * Wdim + t]
            + ws_scores[1 * (Bdim * Wdim) + b * Wdim + t]
            + ws_scores[2 * (Bdim * Wdim) + b * Wdim + t]
            + ws_scores[3 * (Bdim * Wdim) + b * Wdim + t];
    float mx = s;
    #pragma unroll
    for (int off = 32; off > 0; off >>= 1) mx = fmaxf(mx, __shfl_xor(mx, off));
    const float e = __expf(s - mx);
    float sm = e;
    #pragma unroll
    for (int off = 32; off > 0; off >>= 1) sm += __shfl_xor(sm, off);
    const float a = e / sm;
    if (c == 0) out[b * Wdim + t] = a;
    attn[t] = a;
  }
  __syncthreads();

  const float* base = inputs + ((size_t)b * Sdim + sl - Wdim) * Hdim + c * 256;
  float a0 = 0.f;
  #pragma unroll 8
  for (int w = 0; w < Wdim; ++w)
    a0 = fmaf(attn[w], base[(size_t)w * Hdim + t], a0);
  out[Bdim * Wdim + (size_t)b * Hdim + c * 256 + t] = a0;

  const float* pr = inputs + ((size_t)b * Sdim + sl - parent[b] - 1) * Hdim + c * 256;
  out[Bdim * Wdim + Bdim * Hdim + (size_t)b * Hdim + c * 256 + t] = pr[t];
}

extern "C" void kernel_launch(void* const* d_in, const int* in_sizes, int n_in,
                              void* d_out, int out_size, void* d_ws, size_t ws_size,
                              hipStream_t stream) {
  const float* inputs = (const float*)d_in[0];
  const float* hc     = (const float*)d_in[1];
  const float* Wa     = (const float*)d_in[2];
  const float* ba     = (const float*)d_in[3];
  const float* v      = (const float*)d_in[4];
  const int*   slen   = (const int*)d_in[5];
  const int*   parent = (const int*)d_in[6];
  float* out = (float*)d_out;
  float* ws  = (float*)d_ws;
  float* part = ws + WS_SCORES_F;
  unsigned short* wsp = (unsigned short*)(ws + WS_SCORES_F + WS_PART_F);

  if (ws_size >= WS_MFMA_BYTES) {
    k_wsplit<<<dim3(Hdim), 256, 0, stream>>>(Wa, wsp);
    k_hcw<<<dim3(NJT, 16, KC), 256, 0, stream>>>(hc, Wa, part);
    k_scores_mfma<<<dim3(NJT, Bdim / 4), 512, 0, stream>>>(
        inputs, ba, v, slen, ws, part, wsp);
  } else if (ws_size >= WS_NEED_BYTES) {
    k_hcw<<<dim3(NJT, 16, KC), 256, 0, stream>>>(hc, Wa, part);
    k_scores<1><<<dim3(NJT, Bdim / 2), 256, 0, stream>>>(
        inputs, hc, Wa, ba, v, slen, ws, part);
  } else {
    k_scores<0><<<dim3(NJT, Bdim / 2), 256, 0, stream>>>(
        inputs, hc, Wa, ba, v, slen, ws, nullptr);
  }
  k_finish<<<dim3(Bdim, 4), 256, 0, stream>>>(inputs, slen, parent, ws, out);
}